// Round 7
// baseline (17129.099 us; speedup 1.0000x reference)
//
#include <hip/hip_runtime.h>

#define T_STEPS 256
#define B_SZ 256
#define H_SZ 1792
#define IN_SZ 160
#define BH (B_SZ * H_SZ) /* 458752 */
#define NSTEP_REC 56
#define NSTEP_X 5
#define NFRAG_H 112
#define APK_HALF (16 * NSTEP_REC * 2 * 512) /* fp16 elems per A buffer */
#define NBLOCKS 224

typedef __attribute__((ext_vector_type(8))) _Float16 f16x8;
typedef __attribute__((ext_vector_type(4))) _Float16 f16x4;
typedef __attribute__((ext_vector_type(4))) float f32x4;

__device__ __forceinline__ unsigned rotl32(unsigned x, int r) {
  return (x << r) | (x >> (32 - r));
}

__device__ __forceinline__ void threefry2x32(unsigned k0, unsigned k1,
                                             unsigned x0, unsigned x1,
                                             unsigned& o0, unsigned& o1) {
  unsigned ks2 = k0 ^ k1 ^ 0x1BD11BDAu;
  x0 += k0; x1 += k1;
#define TF_R(r) { x0 += x1; x1 = rotl32(x1, (r)); x1 ^= x0; }
  TF_R(13) TF_R(15) TF_R(26) TF_R(6)
  x0 += k1; x1 += ks2 + 1u;
  TF_R(17) TF_R(29) TF_R(16) TF_R(24)
  x0 += ks2; x1 += k0 + 2u;
  TF_R(13) TF_R(15) TF_R(26) TF_R(6)
  x0 += k0; x1 += k1 + 3u;
  TF_R(17) TF_R(29) TF_R(16) TF_R(24)
  x0 += k1; x1 += ks2 + 4u;
  TF_R(13) TF_R(15) TF_R(26) TF_R(6)
  x0 += ks2; x1 += k0 + 5u;
#undef TF_R
  o0 = x0; o1 = x1;
}

__device__ __forceinline__ float erfinv_f32(float x) {
  float w = -log1pf(-x * x);
  float p;
  if (w < 5.0f) {
    w -= 2.5f;
    p = 2.81022636e-08f;
    p = fmaf(p, w, 3.43273939e-07f);
    p = fmaf(p, w, -3.5233877e-06f);
    p = fmaf(p, w, -4.39150654e-06f);
    p = fmaf(p, w, 0.00021858087f);
    p = fmaf(p, w, -0.00125372503f);
    p = fmaf(p, w, -0.00417768164f);
    p = fmaf(p, w, 0.246640727f);
    p = fmaf(p, w, 1.50140941f);
  } else {
    w = sqrtf(w) - 3.0f;
    p = -0.000200214257f;
    p = fmaf(p, w, 0.000100950558f);
    p = fmaf(p, w, 0.00134934322f);
    p = fmaf(p, w, -0.00367342844f);
    p = fmaf(p, w, 0.00573950773f);
    p = fmaf(p, w, -0.0076224613f);
    p = fmaf(p, w, 0.00943887047f);
    p = fmaf(p, w, 1.00167406f);
    p = fmaf(p, w, 2.83297682f);
  }
  return p * x;
}

// JAX partitionable threefry bits = o0 ^ o1 of threefry(key, (0, e)).
__device__ __forceinline__ float jax_normal(unsigned k0, unsigned k1, unsigned e) {
  unsigned o0, o1;
  threefry2x32(k0, k1, 0u, e, o0, o1);
  const unsigned bits = o0 ^ o1;
  float u = __uint_as_float((bits >> 9) | 0x3F800000u) - 1.0f;
  float z = u * 2.0f + (-0.99999994f);
  z = fmaxf(-0.99999994f, z);
  return 1.4142135623730951f * erfinv_f32(z);
}

__global__ void init_keys_kernel(unsigned* __restrict__ keybuf,
                                 unsigned* __restrict__ bar) {
  const unsigned t = threadIdx.x;
  unsigned o0, o1;
  threefry2x32(0u, 42u, 0u, t, o0, o1);
  keybuf[2 * t] = o0;
  keybuf[2 * t + 1] = o1;
  if (t == 0) bar[0] = 0u; // arrival counter (bar[1] = generation, relative)
}

// fp16 2-way split: w ~= h + m/2048 (m pre-scaled to stay normal).
__device__ __forceinline__ void split2(float w, _Float16& h, _Float16& m) {
  h = (_Float16)w;
  float r = w - (float)h;
  m = (_Float16)(r * 2048.0f);
}

// B_pk[s][f][p][512] : frag elem(lane,j) = B[k=32s+8*(lane>>4)+j][h=16f+(lane&15)]
__global__ void pack_B_kernel(const float* __restrict__ W_in,
                              const float* __restrict__ W_rec,
                              _Float16* __restrict__ Bpk) {
  const int id = blockIdx.x * 256 + threadIdx.x; // 437248
  const int h = id / 244;
  const int ko = id - h * 244;
  const int k0 = ko * 8;
  float w[8];
  if (k0 < H_SZ) {
    const float4* src = reinterpret_cast<const float4*>(&W_rec[(size_t)h * H_SZ + k0]);
    float4 v0 = src[0], v1 = src[1];
    float m;
    if (h < 512)       m = (k0 < 1536) ? 1.0f : 0.0f;
    else if (h < 1536) m = 1.0f;
    else               m = (k0 >= 512) ? 1.0f : 0.0f;
    w[0]=v0.x*m; w[1]=v0.y*m; w[2]=v0.z*m; w[3]=v0.w*m;
    w[4]=v1.x*m; w[5]=v1.y*m; w[6]=v1.z*m; w[7]=v1.w*m;
  } else {
    const int i0 = k0 - H_SZ;
    const float4* src = reinterpret_cast<const float4*>(&W_in[(size_t)h * IN_SZ + i0]);
    float4 v0 = src[0], v1 = src[1];
    float m;
    if (h < 512)       m = (i0 < 128) ? 1.0f : 0.0f;
    else if (h < 1536) m = (i0 >= 128) ? 1.0f : 0.0f;
    else               m = (i0 >= 64 && i0 < 128) ? 1.0f : 0.0f;
    w[0]=v0.x*m; w[1]=v0.y*m; w[2]=v0.z*m; w[3]=v0.w*m;
    w[4]=v1.x*m; w[5]=v1.y*m; w[6]=v1.z*m; w[7]=v1.w*m;
  }
  f16x8 vh, vm;
#pragma unroll
  for (int j = 0; j < 8; ++j) {
    _Float16 a, b;
    split2(w[j], a, b);
    vh[j] = a; vm[j] = b;
  }
  const int s = ko >> 2;
  const int f = h >> 4;
  const int lane = (h & 15) + 16 * (ko & 3);
  _Float16* dst = Bpk + ((size_t)(s * NFRAG_H + f) * 2) * 512 + lane * 8;
  *reinterpret_cast<f16x8*>(dst)       = vh;
  *reinterpret_cast<f16x8*>(dst + 512) = vm;
}

// X_pk[t][bf][sx][p][512] : elem(lane,j) = x[t][b=16bf+(lane&15)][i=32sx+8*(lane>>4)+j]
__global__ void pack_x_kernel(const float* __restrict__ inputs,
                              _Float16* __restrict__ Xpk) {
  const int id = blockIdx.x * 256 + threadIdx.x; // 1310720
  const int io = id % 20;
  const int tb = id / 20;
  const int b = tb & 255;
  const int t = tb >> 8;
  const float4* src = reinterpret_cast<const float4*>(
      &inputs[((size_t)(t * 256 + b)) * IN_SZ + io * 8]);
  float4 v0 = src[0], v1 = src[1];
  float w[8] = {v0.x, v0.y, v0.z, v0.w, v1.x, v1.y, v1.z, v1.w};
  f16x8 vh, vm;
#pragma unroll
  for (int j = 0; j < 8; ++j) {
    _Float16 a, bb;
    split2(w[j], a, bb);
    vh[j] = a; vm[j] = bb;
  }
  const int sx = io >> 2;
  const int lane = (b & 15) + 16 * (io & 3);
  _Float16* dst = Xpk +
      ((size_t)((t * 16 + (b >> 4)) * NSTEP_X + sx) * 2) * 512 + lane * 8;
  *reinterpret_cast<f16x8*>(dst)       = vh;
  *reinterpret_cast<f16x8*>(dst + 512) = vm;
}

__global__ void zero_kernel(float* __restrict__ p, int n) {
  const int i = blockIdx.x * 256 + threadIdx.x;
  if (i < n) p[i] = 0.0f;
}

__device__ __forceinline__ void grid_barrier(unsigned* bar) {
  __syncthreads();
  if (threadIdx.x == 0) {
    __threadfence(); // release our step's global writes (device scope)
    const unsigned gen = __hip_atomic_load(bar + 1, __ATOMIC_RELAXED,
                                           __HIP_MEMORY_SCOPE_AGENT);
    const unsigned pos = __hip_atomic_fetch_add(bar, 1u, __ATOMIC_ACQ_REL,
                                                __HIP_MEMORY_SCOPE_AGENT);
    if (pos == NBLOCKS - 1) {
      __hip_atomic_store(bar, 0u, __ATOMIC_RELAXED, __HIP_MEMORY_SCOPE_AGENT);
      __hip_atomic_store(bar + 1, gen + 1u, __ATOMIC_RELEASE,
                         __HIP_MEMORY_SCOPE_AGENT);
    } else {
      while (__hip_atomic_load(bar + 1, __ATOMIC_ACQUIRE,
                               __HIP_MEMORY_SCOPE_AGENT) == gen) {
        __builtin_amdgcn_s_sleep(2);
      }
    }
    __threadfence(); // acquire: invalidate stale L1/L2 before next step's reads
  }
  __syncthreads();
}

// Persistent: 224 blocks x 512 thr (8 waves), all 256 steps + final write.
// Per step: wave-disjoint split-k (wave w: s = w, w+8, ...), B 3-deep / A
// 2-deep register pipeline, LDS reduce, fused noise/state/ReLU, A-repack.
__global__ __launch_bounds__(512, 2) void eirnn_persist(
    _Float16* __restrict__ Apk,
    const _Float16* __restrict__ Xpk,
    const _Float16* __restrict__ Bpk,
    const float* __restrict__ b_in, const float* __restrict__ b_rec,
    const unsigned* __restrict__ keybuf,
    float* __restrict__ out, unsigned* __restrict__ bar) {
  __shared__ float ldsC[8][32][68];

  const int tid = threadIdx.x;
  const int w = tid >> 6;
  const int lane = tid & 63;
  // XCD-chunked swizzle: each XCD owns a contiguous logical range.
  const int logical = (blockIdx.x & 7) * 28 + (blockIdx.x >> 3);
  const int hb = logical >> 3; // 0..27
  const int bb = logical & 7;  // 0..7
  const int b0 = bb * 32;

  const int bl = tid >> 4; // 0..31
  const int q  = tid & 15; // 0..15
  const int h0 = hb * 64 + q * 4;
  const size_t e0 = (size_t)(b0 + bl) * H_SZ + h0;
  const unsigned eb = (unsigned)e0;
  const float sig = (h0 < 1024 || h0 >= 1536) ? 0.1f : 0.0f;

  const int bf0 = b0 >> 4;
  const int f0 = hb * 4;
  const int lofs = lane * 8;

  const f32x4 bi = *reinterpret_cast<const f32x4*>(&b_in[h0]);
  const f32x4 br = *reinterpret_cast<const f32x4*>(&b_rec[h0]);

  // A-repack destination geometry (constant per thread)
  const int bfull = b0 + bl;
  const size_t apk_off = ((size_t)((bfull >> 4) * NSTEP_REC + hb * 2 + (q >> 3)) * 2) * 512 +
                         ((bfull & 15) + 16 * ((q >> 1) & 3)) * 8 + (q & 1) * 4;

  f32x4 sv = {0.0f, 0.0f, 0.0f, 0.0f}; // state lives in registers
  _Float16* Ac = Apk;              // current A (zeroed for t=0 by prologue)
  _Float16* An = Apk + APK_HALF;   // next A

  f16x8 bA[2][2][2]; // [buf][pi][plane]
  f16x8 bB[3][4][2]; // [buf][qi][plane]

#define LA(IA, S)                                                              \
  { _Pragma("unroll")                                                          \
    for (int pi = 0; pi < 2; ++pi) {                                           \
      const _Float16* ap =                                                     \
          Ac + ((size_t)((bf0 + pi) * NSTEP_REC + (S)) * 2) * 512 + lofs;      \
      bA[IA][pi][0] = *reinterpret_cast<const f16x8*>(ap);                     \
      bA[IA][pi][1] = *reinterpret_cast<const f16x8*>(ap + 512);               \
    } }
#define LB(IB, S)                                                              \
  { _Pragma("unroll")                                                          \
    for (int qi = 0; qi < 4; ++qi) {                                           \
      const _Float16* bp =                                                     \
          Bpk + ((size_t)((S) * NFRAG_H + f0 + qi) * 2) * 512 + lofs;          \
      bB[IB][qi][0] = *reinterpret_cast<const f16x8*>(bp);                     \
      bB[IB][qi][1] = *reinterpret_cast<const f16x8*>(bp + 512);               \
    } }
#define LAX(IA, SX)                                                            \
  { _Pragma("unroll")                                                          \
    for (int pi = 0; pi < 2; ++pi) {                                           \
      const _Float16* ap =                                                     \
          Xt + ((size_t)((bf0 + pi) * NSTEP_X + (SX)) * 2) * 512 + lofs;       \
      bA[IA][pi][0] = *reinterpret_cast<const f16x8*>(ap);                     \
      bA[IA][pi][1] = *reinterpret_cast<const f16x8*>(ap + 512);               \
    } }
#define LBX(IB, SX)                                                            \
  { _Pragma("unroll")                                                          \
    for (int qi = 0; qi < 4; ++qi) {                                           \
      const _Float16* bp =                                                     \
          Bpk + ((size_t)((NSTEP_REC + (SX)) * NFRAG_H + f0 + qi) * 2) * 512 + lofs; \
      bB[IB][qi][0] = *reinterpret_cast<const f16x8*>(bp);                     \
      bB[IB][qi][1] = *reinterpret_cast<const f16x8*>(bp + 512);               \
    } }
#define MM(IB, IA)                                                             \
  { _Pragma("unroll")                                                          \
    for (int pi = 0; pi < 2; ++pi)                                             \
      _Pragma("unroll")                                                        \
      for (int qi = 0; qi < 4; ++qi) {                                         \
        acc1[pi][qi] = __builtin_amdgcn_mfma_f32_16x16x32_f16(                 \
            bA[IA][pi][0], bB[IB][qi][0], acc1[pi][qi], 0, 0, 0);              \
        acc2[pi][qi] = __builtin_amdgcn_mfma_f32_16x16x32_f16(                 \
            bA[IA][pi][0], bB[IB][qi][1], acc2[pi][qi], 0, 0, 0);              \
        acc2[pi][qi] = __builtin_amdgcn_mfma_f32_16x16x32_f16(                 \
            bA[IA][pi][1], bB[IB][qi][0], acc2[pi][qi], 0, 0, 0);              \
      } }

  for (int t = 0; t < T_STEPS; ++t) {
    const _Float16* Xt = Xpk + (size_t)t * (16 * NSTEP_X * 2 * 512);
    f32x4 acc1[2][4] = {};
    f32x4 acc2[2][4] = {};

    LA(0, w) LB(0, w)
    LA(1, w + 8) LB(1, w + 8)

    // noise for this step: VALU-only, overlaps the initial load latency
    float nz[4] = {0.0f, 0.0f, 0.0f, 0.0f};
    if (sig != 0.0f) {
      const unsigned kk0 = keybuf[2 * t], kk1 = keybuf[2 * t + 1];
#pragma unroll
      for (int j = 0; j < 4; ++j) nz[j] = jax_normal(kk0, kk1, eb + j);
    }

    LB(2, w + 16) MM(0, 0) LA(0, w + 16)
    LB(0, w + 24) MM(1, 1) LA(1, w + 24)
    LB(1, w + 32) MM(2, 0) LA(0, w + 32)
    LB(2, w + 40) MM(0, 1) LA(1, w + 40)
    LB(0, w + 48) MM(1, 0) LA(0, w + 48)
    if (w < 5) { LBX(1, w) MM(2, 1) LAX(1, w) }
    else       { MM(2, 1) }
    MM(0, 0)
    if (w < 5) { MM(1, 1) }

    // scatter partials: row = b-local, col = h-local (validated mapping)
#pragma unroll
    for (int pi = 0; pi < 2; ++pi)
#pragma unroll
      for (int qi = 0; qi < 4; ++qi) {
        const int row = pi * 16 + ((lane >> 4) << 2);
        const int col = qi * 16 + (lane & 15);
#pragma unroll
        for (int r = 0; r < 4; ++r)
          ldsC[w][row + r][col] =
              acc1[pi][qi][r] + acc2[pi][qi][r] * (1.0f / 2048.0f);
      }
    __syncthreads();

    f32x4 sum = {0.0f, 0.0f, 0.0f, 0.0f};
#pragma unroll
    for (int ww = 0; ww < 8; ++ww)
      sum += *reinterpret_cast<const f32x4*>(&ldsC[ww][bl][q * 4]);

    f32x4 so, oo;
    f16x4 vh, vm;
#pragma unroll
    for (int j = 0; j < 4; ++j) {
      float s = sv[j] * 0.6666666865348816f +
                (sum[j] + bi[j] + br[j]) * 0.3333333432674408f;
      s += sig * nz[j];
      const float o = fmaxf(s, 0.0f);
      so[j] = s; oo[j] = o;
      _Float16 xh, xm;
      split2(o, xh, xm);
      vh[j] = xh; vm[j] = xm;
    }
    sv = so;
    *reinterpret_cast<f32x4*>(&out[(size_t)t * BH + e0]) = oo;

    if (t < T_STEPS - 1) {
      _Float16* dst = An + apk_off;
      *reinterpret_cast<f16x4*>(dst)       = vh;
      *reinterpret_cast<f16x4*>(dst + 512) = vm;
      grid_barrier(bar);
      _Float16* tmp = Ac; Ac = An; An = tmp;
    } else {
      // final (state, out) appended after the T outputs
      *reinterpret_cast<f32x4*>(&out[(size_t)T_STEPS * BH + e0]) = so;
      *reinterpret_cast<f32x4*>(&out[(size_t)T_STEPS * BH + BH + e0]) = oo;
    }
  }
#undef LA
#undef LB
#undef LAX
#undef LBX
#undef MM
}

extern "C" void kernel_launch(void* const* d_in, const int* in_sizes, int n_in,
                              void* d_out, int out_size, void* d_ws, size_t ws_size,
                              hipStream_t stream) {
  const float* inputs = (const float*)d_in[0];
  const float* W_in   = (const float*)d_in[1];
  const float* b_in   = (const float*)d_in[2];
  const float* W_rec  = (const float*)d_in[3];
  const float* b_rec  = (const float*)d_in[4];
  float* out = (float*)d_out;

  char* ws = (char*)d_ws;
  _Float16* Bpk = (_Float16*)ws;                 // 13,991,936 B
  _Float16* Xpk = (_Float16*)(ws + 13991936);    // 41,943,040 B
  _Float16* Apk = (_Float16*)(ws + 55934976);    // 3,670,016 B
  unsigned* keybuf = (unsigned*)(ws + 59604992); // 2,048 B
  unsigned* bar = (unsigned*)(ws + 59607168);    // 128 B, own cacheline

  init_keys_kernel<<<1, 256, 0, stream>>>(keybuf, bar);
  pack_B_kernel<<<1708, 256, 0, stream>>>(W_in, W_rec, Bpk);
  pack_x_kernel<<<5120, 256, 0, stream>>>(inputs, Xpk);
  zero_kernel<<<1792, 256, 0, stream>>>((float*)Apk, APK_HALF / 2); // A buf0 = 0

  eirnn_persist<<<NBLOCKS, 512, 0, stream>>>(
      Apk, Xpk, Bpk, b_in, b_rec, keybuf, out, bar);
}

// Round 8
// 10532.696 us; speedup vs baseline: 1.6263x; 1.6263x over previous
//
#include <hip/hip_runtime.h>

#define T_STEPS 256
#define B_SZ 256
#define H_SZ 1792
#define IN_SZ 160
#define BH (B_SZ * H_SZ) /* 458752 */
#define NSTEP_REC 56
#define NSTEP_X 5
#define NFRAG_H 112
#define APK_HALF (16 * NSTEP_REC * 2 * 512) /* fp16 elems per A buffer */
#define NBLOCKS 224

typedef __attribute__((ext_vector_type(8))) _Float16 f16x8;
typedef __attribute__((ext_vector_type(4))) _Float16 f16x4;
typedef __attribute__((ext_vector_type(4))) float f32x4;
typedef unsigned long long u64;

union U64F16x8 { u64 u[2]; f16x8 v; };
union U64F16x4 { u64 u; f16x4 v; };

__device__ __forceinline__ unsigned rotl32(unsigned x, int r) {
  return (x << r) | (x >> (32 - r));
}

__device__ __forceinline__ void threefry2x32(unsigned k0, unsigned k1,
                                             unsigned x0, unsigned x1,
                                             unsigned& o0, unsigned& o1) {
  unsigned ks2 = k0 ^ k1 ^ 0x1BD11BDAu;
  x0 += k0; x1 += k1;
#define TF_R(r) { x0 += x1; x1 = rotl32(x1, (r)); x1 ^= x0; }
  TF_R(13) TF_R(15) TF_R(26) TF_R(6)
  x0 += k1; x1 += ks2 + 1u;
  TF_R(17) TF_R(29) TF_R(16) TF_R(24)
  x0 += ks2; x1 += k0 + 2u;
  TF_R(13) TF_R(15) TF_R(26) TF_R(6)
  x0 += k0; x1 += k1 + 3u;
  TF_R(17) TF_R(29) TF_R(16) TF_R(24)
  x0 += k1; x1 += ks2 + 4u;
  TF_R(13) TF_R(15) TF_R(26) TF_R(6)
  x0 += ks2; x1 += k0 + 5u;
#undef TF_R
  o0 = x0; o1 = x1;
}

__device__ __forceinline__ float erfinv_f32(float x) {
  float w = -log1pf(-x * x);
  float p;
  if (w < 5.0f) {
    w -= 2.5f;
    p = 2.81022636e-08f;
    p = fmaf(p, w, 3.43273939e-07f);
    p = fmaf(p, w, -3.5233877e-06f);
    p = fmaf(p, w, -4.39150654e-06f);
    p = fmaf(p, w, 0.00021858087f);
    p = fmaf(p, w, -0.00125372503f);
    p = fmaf(p, w, -0.00417768164f);
    p = fmaf(p, w, 0.246640727f);
    p = fmaf(p, w, 1.50140941f);
  } else {
    w = sqrtf(w) - 3.0f;
    p = -0.000200214257f;
    p = fmaf(p, w, 0.000100950558f);
    p = fmaf(p, w, 0.00134934322f);
    p = fmaf(p, w, -0.00367342844f);
    p = fmaf(p, w, 0.00573950773f);
    p = fmaf(p, w, -0.0076224613f);
    p = fmaf(p, w, 0.00943887047f);
    p = fmaf(p, w, 1.00167406f);
    p = fmaf(p, w, 2.83297682f);
  }
  return p * x;
}

// JAX partitionable threefry bits = o0 ^ o1 of threefry(key, (0, e)).
__device__ __forceinline__ float jax_normal(unsigned k0, unsigned k1, unsigned e) {
  unsigned o0, o1;
  threefry2x32(k0, k1, 0u, e, o0, o1);
  const unsigned bits = o0 ^ o1;
  float u = __uint_as_float((bits >> 9) | 0x3F800000u) - 1.0f;
  float z = u * 2.0f + (-0.99999994f);
  z = fmaxf(-0.99999994f, z);
  return 1.4142135623730951f * erfinv_f32(z);
}

__global__ void init_keys_kernel(unsigned* __restrict__ keybuf,
                                 unsigned* __restrict__ bar) {
  const unsigned t = threadIdx.x;
  unsigned o0, o1;
  threefry2x32(0u, 42u, 0u, t, o0, o1);
  keybuf[2 * t] = o0;
  keybuf[2 * t + 1] = o1;
  if (t == 0) bar[0] = 0u; // arrival counter (bar[1] = generation, relative)
}

// fp16 2-way split: w ~= h + m/2048 (m pre-scaled to stay normal).
__device__ __forceinline__ void split2(float w, _Float16& h, _Float16& m) {
  h = (_Float16)w;
  float r = w - (float)h;
  m = (_Float16)(r * 2048.0f);
}

// B_pk[s][f][p][512] : frag elem(lane,j) = B[k=32s+8*(lane>>4)+j][h=16f+(lane&15)]
__global__ void pack_B_kernel(const float* __restrict__ W_in,
                              const float* __restrict__ W_rec,
                              _Float16* __restrict__ Bpk) {
  const int id = blockIdx.x * 256 + threadIdx.x; // 437248
  const int h = id / 244;
  const int ko = id - h * 244;
  const int k0 = ko * 8;
  float w[8];
  if (k0 < H_SZ) {
    const float4* src = reinterpret_cast<const float4*>(&W_rec[(size_t)h * H_SZ + k0]);
    float4 v0 = src[0], v1 = src[1];
    float m;
    if (h < 512)       m = (k0 < 1536) ? 1.0f : 0.0f;
    else if (h < 1536) m = 1.0f;
    else               m = (k0 >= 512) ? 1.0f : 0.0f;
    w[0]=v0.x*m; w[1]=v0.y*m; w[2]=v0.z*m; w[3]=v0.w*m;
    w[4]=v1.x*m; w[5]=v1.y*m; w[6]=v1.z*m; w[7]=v1.w*m;
  } else {
    const int i0 = k0 - H_SZ;
    const float4* src = reinterpret_cast<const float4*>(&W_in[(size_t)h * IN_SZ + i0]);
    float4 v0 = src[0], v1 = src[1];
    float m;
    if (h < 512)       m = (i0 < 128) ? 1.0f : 0.0f;
    else if (h < 1536) m = (i0 >= 128) ? 1.0f : 0.0f;
    else               m = (i0 >= 64 && i0 < 128) ? 1.0f : 0.0f;
    w[0]=v0.x*m; w[1]=v0.y*m; w[2]=v0.z*m; w[3]=v0.w*m;
    w[4]=v1.x*m; w[5]=v1.y*m; w[6]=v1.z*m; w[7]=v1.w*m;
  }
  f16x8 vh, vm;
#pragma unroll
  for (int j = 0; j < 8; ++j) {
    _Float16 a, b;
    split2(w[j], a, b);
    vh[j] = a; vm[j] = b;
  }
  const int s = ko >> 2;
  const int f = h >> 4;
  const int lane = (h & 15) + 16 * (ko & 3);
  _Float16* dst = Bpk + ((size_t)(s * NFRAG_H + f) * 2) * 512 + lane * 8;
  *reinterpret_cast<f16x8*>(dst)       = vh;
  *reinterpret_cast<f16x8*>(dst + 512) = vm;
}

// X_pk[t][bf][sx][p][512] : elem(lane,j) = x[t][b=16bf+(lane&15)][i=32sx+8*(lane>>4)+j]
__global__ void pack_x_kernel(const float* __restrict__ inputs,
                              _Float16* __restrict__ Xpk) {
  const int id = blockIdx.x * 256 + threadIdx.x; // 1310720
  const int io = id % 20;
  const int tb = id / 20;
  const int b = tb & 255;
  const int t = tb >> 8;
  const float4* src = reinterpret_cast<const float4*>(
      &inputs[((size_t)(t * 256 + b)) * IN_SZ + io * 8]);
  float4 v0 = src[0], v1 = src[1];
  float w[8] = {v0.x, v0.y, v0.z, v0.w, v1.x, v1.y, v1.z, v1.w};
  f16x8 vh, vm;
#pragma unroll
  for (int j = 0; j < 8; ++j) {
    _Float16 a, bb;
    split2(w[j], a, bb);
    vh[j] = a; vm[j] = bb;
  }
  const int sx = io >> 2;
  const int lane = (b & 15) + 16 * (io & 3);
  _Float16* dst = Xpk +
      ((size_t)((t * 16 + (b >> 4)) * NSTEP_X + sx) * 2) * 512 + lane * 8;
  *reinterpret_cast<f16x8*>(dst)       = vh;
  *reinterpret_cast<f16x8*>(dst + 512) = vm;
}

__global__ void zero_kernel(float* __restrict__ p, int n) {
  const int i = blockIdx.x * 256 + threadIdx.x;
  if (i < n) p[i] = 0.0f;
}

// Fence-free grid barrier. NO __threadfence (that lowers to buffer_wbl2 +
// buffer_inv = full L2 flush per step — R7's 5x regression). Visibility of
// A-fragments is guaranteed by: producers write A with AGENT-scope atomic
// stores (write-through to IF), each wave's stores drain (vmcnt(0)) at the
// compiler-emitted waitcnt before s_barrier below, and consumers read A with
// AGENT-scope atomic loads (bypass L1/L2) after the spin exits.
__device__ __forceinline__ void grid_barrier(unsigned* bar) {
  __syncthreads(); // drains all waves' outstanding stores (vmcnt 0 each)
  if (threadIdx.x == 0) {
    const unsigned gen = __hip_atomic_load(bar + 1, __ATOMIC_RELAXED,
                                           __HIP_MEMORY_SCOPE_AGENT);
    const unsigned pos = __hip_atomic_fetch_add(bar, 1u, __ATOMIC_RELAXED,
                                                __HIP_MEMORY_SCOPE_AGENT);
    if (pos == NBLOCKS - 1) {
      __hip_atomic_store(bar, 0u, __ATOMIC_RELAXED, __HIP_MEMORY_SCOPE_AGENT);
      __hip_atomic_store(bar + 1, gen + 1u, __ATOMIC_RELAXED,
                         __HIP_MEMORY_SCOPE_AGENT);
    } else {
      while (__hip_atomic_load(bar + 1, __ATOMIC_RELAXED,
                               __HIP_MEMORY_SCOPE_AGENT) == gen) {
        __builtin_amdgcn_s_sleep(2);
      }
    }
  }
  asm volatile("" ::: "memory"); // compiler fence only (no cache ops)
  __syncthreads();
}

// Persistent: 224 blocks x 512 thr (8 waves), all 256 steps + final write.
// Per step: wave-disjoint split-k, B 3-deep / A 2-deep register pipeline,
// LDS reduce, fused noise/state/ReLU, A-repack via coherent stores.
__global__ __launch_bounds__(512, 2) void eirnn_persist(
    _Float16* __restrict__ Apk,
    const _Float16* __restrict__ Xpk,
    const _Float16* __restrict__ Bpk,
    const float* __restrict__ b_in, const float* __restrict__ b_rec,
    const unsigned* __restrict__ keybuf,
    float* __restrict__ out, unsigned* __restrict__ bar) {
  __shared__ float ldsC[8][32][68];

  const int tid = threadIdx.x;
  const int w = tid >> 6;
  const int lane = tid & 63;
  // XCD-chunked swizzle (perf only): contiguous hb range per XCD keeps each
  // XCD's B-panel (~1.75 MB) resident in its L2 across all 256 steps.
  const int logical = (blockIdx.x & 7) * 28 + (blockIdx.x >> 3);
  const int hb = logical >> 3; // 0..27
  const int bb = logical & 7;  // 0..7
  const int b0 = bb * 32;

  const int bl = tid >> 4; // 0..31
  const int q  = tid & 15; // 0..15
  const int h0 = hb * 64 + q * 4;
  const size_t e0 = (size_t)(b0 + bl) * H_SZ + h0;
  const unsigned eb = (unsigned)e0;
  const float sig = (h0 < 1024 || h0 >= 1536) ? 0.1f : 0.0f;

  const int bf0 = b0 >> 4;
  const int f0 = hb * 4;
  const int lofs = lane * 8;

  const f32x4 bi = *reinterpret_cast<const f32x4*>(&b_in[h0]);
  const f32x4 br = *reinterpret_cast<const f32x4*>(&b_rec[h0]);

  const int bfull = b0 + bl;
  const size_t apk_off = ((size_t)((bfull >> 4) * NSTEP_REC + hb * 2 + (q >> 3)) * 2) * 512 +
                         ((bfull & 15) + 16 * ((q >> 1) & 3)) * 8 + (q & 1) * 4;

  f32x4 sv = {0.0f, 0.0f, 0.0f, 0.0f}; // state lives in registers
  _Float16* Ac = Apk;
  _Float16* An = Apk + APK_HALF;

  f16x8 bA[2][2][2]; // [buf][pi][plane]
  f16x8 bB[3][4][2]; // [buf][qi][plane]

// A loads: AGENT-scope relaxed atomic 8B loads (sc flags -> bypass L1 and
// non-home L2), so cross-XCD-produced fragments are always fresh.
#define LA(IA, S)                                                              \
  { _Pragma("unroll")                                                          \
    for (int pi = 0; pi < 2; ++pi) {                                           \
      const u64* ap = (const u64*)(                                            \
          Ac + ((size_t)((bf0 + pi) * NSTEP_REC + (S)) * 2) * 512 + lofs);     \
      U64F16x8 t0, t1;                                                         \
      t0.u[0] = __hip_atomic_load(ap + 0, __ATOMIC_RELAXED,                    \
                                  __HIP_MEMORY_SCOPE_AGENT);                   \
      t0.u[1] = __hip_atomic_load(ap + 1, __ATOMIC_RELAXED,                    \
                                  __HIP_MEMORY_SCOPE_AGENT);                   \
      t1.u[0] = __hip_atomic_load(ap + 128, __ATOMIC_RELAXED,                  \
                                  __HIP_MEMORY_SCOPE_AGENT);                   \
      t1.u[1] = __hip_atomic_load(ap + 129, __ATOMIC_RELAXED,                  \
                                  __HIP_MEMORY_SCOPE_AGENT);                   \
      bA[IA][pi][0] = t0.v;                                                    \
      bA[IA][pi][1] = t1.v;                                                    \
    } }
#define LB(IB, S)                                                              \
  { _Pragma("unroll")                                                          \
    for (int qi = 0; qi < 4; ++qi) {                                           \
      const _Float16* bp =                                                     \
          Bpk + ((size_t)((S) * NFRAG_H + f0 + qi) * 2) * 512 + lofs;          \
      bB[IB][qi][0] = *reinterpret_cast<const f16x8*>(bp);                     \
      bB[IB][qi][1] = *reinterpret_cast<const f16x8*>(bp + 512);               \
    } }
#define LAX(IA, SX)                                                            \
  { _Pragma("unroll")                                                          \
    for (int pi = 0; pi < 2; ++pi) {                                           \
      const _Float16* ap =                                                     \
          Xt + ((size_t)((bf0 + pi) * NSTEP_X + (SX)) * 2) * 512 + lofs;       \
      bA[IA][pi][0] = *reinterpret_cast<const f16x8*>(ap);                     \
      bA[IA][pi][1] = *reinterpret_cast<const f16x8*>(ap + 512);               \
    } }
#define LBX(IB, SX)                                                            \
  { _Pragma("unroll")                                                          \
    for (int qi = 0; qi < 4; ++qi) {                                           \
      const _Float16* bp =                                                     \
          Bpk + ((size_t)((NSTEP_REC + (SX)) * NFRAG_H + f0 + qi) * 2) * 512 + lofs; \
      bB[IB][qi][0] = *reinterpret_cast<const f16x8*>(bp);                     \
      bB[IB][qi][1] = *reinterpret_cast<const f16x8*>(bp + 512);               \
    } }
#define MM(IB, IA)                                                             \
  { _Pragma("unroll")                                                          \
    for (int pi = 0; pi < 2; ++pi)                                             \
      _Pragma("unroll")                                                        \
      for (int qi = 0; qi < 4; ++qi) {                                         \
        acc1[pi][qi] = __builtin_amdgcn_mfma_f32_16x16x32_f16(                 \
            bA[IA][pi][0], bB[IB][qi][0], acc1[pi][qi], 0, 0, 0);              \
        acc2[pi][qi] = __builtin_amdgcn_mfma_f32_16x16x32_f16(                 \
            bA[IA][pi][0], bB[IB][qi][1], acc2[pi][qi], 0, 0, 0);              \
        acc2[pi][qi] = __builtin_amdgcn_mfma_f32_16x16x32_f16(                 \
            bA[IA][pi][1], bB[IB][qi][0], acc2[pi][qi], 0, 0, 0);              \
      } }

  for (int t = 0; t < T_STEPS; ++t) {
    const _Float16* Xt = Xpk + (size_t)t * (16 * NSTEP_X * 2 * 512);
    f32x4 acc1[2][4] = {};
    f32x4 acc2[2][4] = {};

    LA(0, w) LB(0, w)
    LA(1, w + 8) LB(1, w + 8)

    // noise for this step: VALU-only, overlaps the initial load latency
    float nz[4] = {0.0f, 0.0f, 0.0f, 0.0f};
    if (sig != 0.0f) {
      const unsigned kk0 = keybuf[2 * t], kk1 = keybuf[2 * t + 1];
#pragma unroll
      for (int j = 0; j < 4; ++j) nz[j] = jax_normal(kk0, kk1, eb + j);
    }

    LB(2, w + 16) MM(0, 0) LA(0, w + 16)
    LB(0, w + 24) MM(1, 1) LA(1, w + 24)
    LB(1, w + 32) MM(2, 0) LA(0, w + 32)
    LB(2, w + 40) MM(0, 1) LA(1, w + 40)
    LB(0, w + 48) MM(1, 0) LA(0, w + 48)
    if (w < 5) { LBX(1, w) MM(2, 1) LAX(1, w) }
    else       { MM(2, 1) }
    MM(0, 0)
    if (w < 5) { MM(1, 1) }

    // scatter partials: row = b-local, col = h-local (validated mapping)
#pragma unroll
    for (int pi = 0; pi < 2; ++pi)
#pragma unroll
      for (int qi = 0; qi < 4; ++qi) {
        const int row = pi * 16 + ((lane >> 4) << 2);
        const int col = qi * 16 + (lane & 15);
#pragma unroll
        for (int r = 0; r < 4; ++r)
          ldsC[w][row + r][col] =
              acc1[pi][qi][r] + acc2[pi][qi][r] * (1.0f / 2048.0f);
      }
    __syncthreads();

    f32x4 sum = {0.0f, 0.0f, 0.0f, 0.0f};
#pragma unroll
    for (int ww = 0; ww < 8; ++ww)
      sum += *reinterpret_cast<const f32x4*>(&ldsC[ww][bl][q * 4]);

    f32x4 so, oo;
    f16x4 vh, vm;
#pragma unroll
    for (int j = 0; j < 4; ++j) {
      float s = sv[j] * 0.6666666865348816f +
                (sum[j] + bi[j] + br[j]) * 0.3333333432674408f;
      s += sig * nz[j];
      const float o = fmaxf(s, 0.0f);
      so[j] = s; oo[j] = o;
      _Float16 xh, xm;
      split2(o, xh, xm);
      vh[j] = xh; vm[j] = xm;
    }
    sv = so;
    *reinterpret_cast<f32x4*>(&out[(size_t)t * BH + e0]) = oo;

    if (t < T_STEPS - 1) {
      // next-step A fragments: AGENT-scope write-through stores (visible at
      // IF once this wave's vmcnt drains at the barrier's s_waitcnt).
      U64F16x4 sh, sm;
      sh.v = vh; sm.v = vm;
      __hip_atomic_store((u64*)(An + apk_off), sh.u, __ATOMIC_RELAXED,
                         __HIP_MEMORY_SCOPE_AGENT);
      __hip_atomic_store((u64*)(An + apk_off + 512), sm.u, __ATOMIC_RELAXED,
                         __HIP_MEMORY_SCOPE_AGENT);
      grid_barrier(bar);
      _Float16* tmp = Ac; Ac = An; An = tmp;
    } else {
      // final (state, out) appended after the T outputs
      *reinterpret_cast<f32x4*>(&out[(size_t)T_STEPS * BH + e0]) = so;
      *reinterpret_cast<f32x4*>(&out[(size_t)T_STEPS * BH + BH + e0]) = oo;
    }
  }
#undef LA
#undef LB
#undef LAX
#undef LBX
#undef MM
}

extern "C" void kernel_launch(void* const* d_in, const int* in_sizes, int n_in,
                              void* d_out, int out_size, void* d_ws, size_t ws_size,
                              hipStream_t stream) {
  const float* inputs = (const float*)d_in[0];
  const float* W_in   = (const float*)d_in[1];
  const float* b_in   = (const float*)d_in[2];
  const float* W_rec  = (const float*)d_in[3];
  const float* b_rec  = (const float*)d_in[4];
  float* out = (float*)d_out;

  char* ws = (char*)d_ws;
  _Float16* Bpk = (_Float16*)ws;                 // 13,991,936 B
  _Float16* Xpk = (_Float16*)(ws + 13991936);    // 41,943,040 B
  _Float16* Apk = (_Float16*)(ws + 55934976);    // 3,670,016 B
  unsigned* keybuf = (unsigned*)(ws + 59604992); // 2,048 B
  unsigned* bar = (unsigned*)(ws + 59607168);    // 128 B, own cacheline

  init_keys_kernel<<<1, 256, 0, stream>>>(keybuf, bar);
  pack_B_kernel<<<1708, 256, 0, stream>>>(W_in, W_rec, Bpk);
  pack_x_kernel<<<5120, 256, 0, stream>>>(inputs, Xpk);
  zero_kernel<<<1792, 256, 0, stream>>>((float*)Apk, APK_HALF / 2); // A buf0 = 0

  eirnn_persist<<<NBLOCKS, 512, 0, stream>>>(
      Apk, Xpk, Bpk, b_in, b_rec, keybuf, out, bar);
}

// Round 9
// 7626.231 us; speedup vs baseline: 2.2461x; 1.3811x over previous
//
#include <hip/hip_runtime.h>

#define T_STEPS 256
#define B_SZ 256
#define H_SZ 1792
#define IN_SZ 160
#define BH (B_SZ * H_SZ) /* 458752 */
#define NSTEP_REC 56
#define NSTEP_X 5
#define NFRAG_H 112
#define APK_HALF (16 * NSTEP_REC * 2 * 512) /* fp16 elems per A buffer */

typedef __attribute__((ext_vector_type(8))) _Float16 f16x8;
typedef __attribute__((ext_vector_type(4))) _Float16 f16x4;
typedef __attribute__((ext_vector_type(4))) float f32x4;

__device__ __forceinline__ unsigned rotl32(unsigned x, int r) {
  return (x << r) | (x >> (32 - r));
}

__device__ __forceinline__ void threefry2x32(unsigned k0, unsigned k1,
                                             unsigned x0, unsigned x1,
                                             unsigned& o0, unsigned& o1) {
  unsigned ks2 = k0 ^ k1 ^ 0x1BD11BDAu;
  x0 += k0; x1 += k1;
#define TF_R(r) { x0 += x1; x1 = rotl32(x1, (r)); x1 ^= x0; }
  TF_R(13) TF_R(15) TF_R(26) TF_R(6)
  x0 += k1; x1 += ks2 + 1u;
  TF_R(17) TF_R(29) TF_R(16) TF_R(24)
  x0 += ks2; x1 += k0 + 2u;
  TF_R(13) TF_R(15) TF_R(26) TF_R(6)
  x0 += k0; x1 += k1 + 3u;
  TF_R(17) TF_R(29) TF_R(16) TF_R(24)
  x0 += k1; x1 += ks2 + 4u;
  TF_R(13) TF_R(15) TF_R(26) TF_R(6)
  x0 += ks2; x1 += k0 + 5u;
#undef TF_R
  o0 = x0; o1 = x1;
}

__device__ __forceinline__ float erfinv_f32(float x) {
  float w = -log1pf(-x * x);
  float p;
  if (w < 5.0f) {
    w -= 2.5f;
    p = 2.81022636e-08f;
    p = fmaf(p, w, 3.43273939e-07f);
    p = fmaf(p, w, -3.5233877e-06f);
    p = fmaf(p, w, -4.39150654e-06f);
    p = fmaf(p, w, 0.00021858087f);
    p = fmaf(p, w, -0.00125372503f);
    p = fmaf(p, w, -0.00417768164f);
    p = fmaf(p, w, 0.246640727f);
    p = fmaf(p, w, 1.50140941f);
  } else {
    w = sqrtf(w) - 3.0f;
    p = -0.000200214257f;
    p = fmaf(p, w, 0.000100950558f);
    p = fmaf(p, w, 0.00134934322f);
    p = fmaf(p, w, -0.00367342844f);
    p = fmaf(p, w, 0.00573950773f);
    p = fmaf(p, w, -0.0076224613f);
    p = fmaf(p, w, 0.00943887047f);
    p = fmaf(p, w, 1.00167406f);
    p = fmaf(p, w, 2.83297682f);
  }
  return p * x;
}

// JAX partitionable threefry bits = o0 ^ o1 of threefry(key, (0, e)).
__device__ __forceinline__ float jax_normal(unsigned k0, unsigned k1, unsigned e) {
  unsigned o0, o1;
  threefry2x32(k0, k1, 0u, e, o0, o1);
  const unsigned bits = o0 ^ o1;
  float u = __uint_as_float((bits >> 9) | 0x3F800000u) - 1.0f;
  float z = u * 2.0f + (-0.99999994f);
  z = fmaxf(-0.99999994f, z);
  return 1.4142135623730951f * erfinv_f32(z);
}

__global__ void init_keys_kernel(unsigned* __restrict__ keybuf) {
  const unsigned t = threadIdx.x;
  unsigned o0, o1;
  threefry2x32(0u, 42u, 0u, t, o0, o1);
  keybuf[2 * t] = o0;
  keybuf[2 * t + 1] = o1;
}

// fp16 2-way split: w ~= h + m/2048 (m pre-scaled to stay normal).
__device__ __forceinline__ void split2(float w, _Float16& h, _Float16& m) {
  h = (_Float16)w;
  float r = w - (float)h;
  m = (_Float16)(r * 2048.0f);
}

// B_pk[s][f][p][512] : frag elem(lane,j) = B[k=32s+8*(lane>>4)+j][h=16f+(lane&15)]
__global__ void pack_B_kernel(const float* __restrict__ W_in,
                              const float* __restrict__ W_rec,
                              _Float16* __restrict__ Bpk) {
  const int id = blockIdx.x * 256 + threadIdx.x; // 437248
  const int h = id / 244;
  const int ko = id - h * 244;
  const int k0 = ko * 8;
  float w[8];
  if (k0 < H_SZ) {
    const float4* src = reinterpret_cast<const float4*>(&W_rec[(size_t)h * H_SZ + k0]);
    float4 v0 = src[0], v1 = src[1];
    float m;
    if (h < 512)       m = (k0 < 1536) ? 1.0f : 0.0f;
    else if (h < 1536) m = 1.0f;
    else               m = (k0 >= 512) ? 1.0f : 0.0f;
    w[0]=v0.x*m; w[1]=v0.y*m; w[2]=v0.z*m; w[3]=v0.w*m;
    w[4]=v1.x*m; w[5]=v1.y*m; w[6]=v1.z*m; w[7]=v1.w*m;
  } else {
    const int i0 = k0 - H_SZ;
    const float4* src = reinterpret_cast<const float4*>(&W_in[(size_t)h * IN_SZ + i0]);
    float4 v0 = src[0], v1 = src[1];
    float m;
    if (h < 512)       m = (i0 < 128) ? 1.0f : 0.0f;
    else if (h < 1536) m = (i0 >= 128) ? 1.0f : 0.0f;
    else               m = (i0 >= 64 && i0 < 128) ? 1.0f : 0.0f;
    w[0]=v0.x*m; w[1]=v0.y*m; w[2]=v0.z*m; w[3]=v0.w*m;
    w[4]=v1.x*m; w[5]=v1.y*m; w[6]=v1.z*m; w[7]=v1.w*m;
  }
  f16x8 vh, vm;
#pragma unroll
  for (int j = 0; j < 8; ++j) {
    _Float16 a, b;
    split2(w[j], a, b);
    vh[j] = a; vm[j] = b;
  }
  const int s = ko >> 2;
  const int f = h >> 4;
  const int lane = (h & 15) + 16 * (ko & 3);
  _Float16* dst = Bpk + ((size_t)(s * NFRAG_H + f) * 2) * 512 + lane * 8;
  *reinterpret_cast<f16x8*>(dst)       = vh;
  *reinterpret_cast<f16x8*>(dst + 512) = vm;
}

// X_pk[t][bf][sx][p][512] : elem(lane,j) = x[t][b=16bf+(lane&15)][i=32sx+8*(lane>>4)+j]
__global__ void pack_x_kernel(const float* __restrict__ inputs,
                              _Float16* __restrict__ Xpk) {
  const int id = blockIdx.x * 256 + threadIdx.x; // 1310720
  const int io = id % 20;
  const int tb = id / 20;
  const int b = tb & 255;
  const int t = tb >> 8;
  const float4* src = reinterpret_cast<const float4*>(
      &inputs[((size_t)(t * 256 + b)) * IN_SZ + io * 8]);
  float4 v0 = src[0], v1 = src[1];
  float w[8] = {v0.x, v0.y, v0.z, v0.w, v1.x, v1.y, v1.z, v1.w};
  f16x8 vh, vm;
#pragma unroll
  for (int j = 0; j < 8; ++j) {
    _Float16 a, bb;
    split2(w[j], a, bb);
    vh[j] = a; vm[j] = bb;
  }
  const int sx = io >> 2;
  const int lane = (b & 15) + 16 * (io & 3);
  _Float16* dst = Xpk +
      ((size_t)((t * 16 + (b >> 4)) * NSTEP_X + sx) * 2) * 512 + lane * 8;
  *reinterpret_cast<f16x8*>(dst)       = vh;
  *reinterpret_cast<f16x8*>(dst + 512) = vm;
}

__global__ void zero_kernel(float* __restrict__ p, int n) {
  const int i = blockIdx.x * 256 + threadIdx.x;
  if (i < n) p[i] = 0.0f;
}

// grid 224 = 8 bb (32b) x 28 hb (64h); 1024 thr = 16 waves (4/SIMD), split-k
// 16 ways: wave w handles k-steps s = w, w+16, w+32, w+48(<61).
__global__ __launch_bounds__(1024) void eirnn_step(
    const _Float16* __restrict__ Apk_cur,
    _Float16* __restrict__ Apk_next,
    const _Float16* __restrict__ Xpk_t,
    const _Float16* __restrict__ Bpk,
    float* __restrict__ state,
    const float* __restrict__ b_in, const float* __restrict__ b_rec,
    const unsigned* __restrict__ keybuf,
    float* __restrict__ out_t, int t) {
  __shared__ float ldsC[16][32][68]; // 139 KB -> 1 block/CU, 16 waves

  const int tid = threadIdx.x;
  const int w = tid >> 6;   // 0..15
  const int lane = tid & 63;
  // XCD-chunked swizzle (perf heuristic only).
  const int logical = (blockIdx.x & 7) * 28 + (blockIdx.x >> 3);
  const int hb = logical >> 3; // 0..27
  const int bb = logical & 7;  // 0..7
  const int b0 = bb * 32;

  // epilogue geometry + noise (waves 0-7 only; VALU overlaps load latency)
  const int bl = tid >> 4; // valid for tid<512: 0..31
  const int q  = tid & 15;
  const int h0 = hb * 64 + q * 4;
  const size_t e0 = (size_t)(b0 + (bl & 31)) * H_SZ + h0;
  const float sig = (h0 < 1024 || h0 >= 1536) ? 0.1f : 0.0f;
  float nz[4] = {0.0f, 0.0f, 0.0f, 0.0f};
  if (tid < 512 && sig != 0.0f) {
    const unsigned kk0 = keybuf[2 * t], kk1 = keybuf[2 * t + 1];
#pragma unroll
    for (int j = 0; j < 4; ++j)
      nz[j] = jax_normal(kk0, kk1, (unsigned)(e0 + j));
  }

  // ---- GEMM: wave-disjoint k-slices, register double-buffer ----
  const int bf0 = b0 >> 4; // 2 A-frags
  const int f0 = hb * 4;   // 4 B-frags
  const int lofs = lane * 8;

  f32x4 acc1[2][4] = {};
  f32x4 acc2[2][4] = {};
  f16x8 bA[2][2][2]; // [buf][pi][plane]
  f16x8 bB[2][4][2]; // [buf][qi][plane]

#define LA(IA, S)                                                              \
  { _Pragma("unroll")                                                          \
    for (int pi = 0; pi < 2; ++pi) {                                           \
      const _Float16* ap =                                                     \
          Apk_cur + ((size_t)((bf0 + pi) * NSTEP_REC + (S)) * 2) * 512 + lofs; \
      bA[IA][pi][0] = *reinterpret_cast<const f16x8*>(ap);                     \
      bA[IA][pi][1] = *reinterpret_cast<const f16x8*>(ap + 512);               \
    } }
#define LB(IB, S)                                                              \
  { _Pragma("unroll")                                                          \
    for (int qi = 0; qi < 4; ++qi) {                                           \
      const _Float16* bp =                                                     \
          Bpk + ((size_t)((S) * NFRAG_H + f0 + qi) * 2) * 512 + lofs;          \
      bB[IB][qi][0] = *reinterpret_cast<const f16x8*>(bp);                     \
      bB[IB][qi][1] = *reinterpret_cast<const f16x8*>(bp + 512);               \
    } }
#define LAX(IA, SX)                                                            \
  { _Pragma("unroll")                                                          \
    for (int pi = 0; pi < 2; ++pi) {                                           \
      const _Float16* ap =                                                     \
          Xpk_t + ((size_t)((bf0 + pi) * NSTEP_X + (SX)) * 2) * 512 + lofs;    \
      bA[IA][pi][0] = *reinterpret_cast<const f16x8*>(ap);                     \
      bA[IA][pi][1] = *reinterpret_cast<const f16x8*>(ap + 512);               \
    } }
#define LBX(IB, SX)                                                            \
  { _Pragma("unroll")                                                          \
    for (int qi = 0; qi < 4; ++qi) {                                           \
      const _Float16* bp =                                                     \
          Bpk + ((size_t)((NSTEP_REC + (SX)) * NFRAG_H + f0 + qi) * 2) * 512 + lofs; \
      bB[IB][qi][0] = *reinterpret_cast<const f16x8*>(bp);                     \
      bB[IB][qi][1] = *reinterpret_cast<const f16x8*>(bp + 512);               \
    } }
#define MM(IB, IA)                                                             \
  { _Pragma("unroll")                                                          \
    for (int pi = 0; pi < 2; ++pi)                                             \
      _Pragma("unroll")                                                        \
      for (int qi = 0; qi < 4; ++qi) {                                         \
        acc1[pi][qi] = __builtin_amdgcn_mfma_f32_16x16x32_f16(                 \
            bA[IA][pi][0], bB[IB][qi][0], acc1[pi][qi], 0, 0, 0);              \
        acc2[pi][qi] = __builtin_amdgcn_mfma_f32_16x16x32_f16(                 \
            bA[IA][pi][0], bB[IB][qi][1], acc2[pi][qi], 0, 0, 0);              \
        acc2[pi][qi] = __builtin_amdgcn_mfma_f32_16x16x32_f16(                 \
            bA[IA][pi][1], bB[IB][qi][0], acc2[pi][qi], 0, 0, 0);              \
      } }

  const int s3 = w + 48; // only slot that can be an X-step or invalid
  LA(0, w) LB(0, w)
  LA(1, w + 16) LB(1, w + 16)
  MM(0, 0)
  LA(0, w + 32) LB(0, w + 32)
  MM(1, 1)
  if (s3 < NSTEP_REC) {
    LA(1, s3) LB(1, s3)
    MM(0, 0) MM(1, 1)
  } else if (s3 < NSTEP_REC + NSTEP_X) {
    LAX(1, s3 - NSTEP_REC) LBX(1, s3 - NSTEP_REC)
    MM(0, 0) MM(1, 1)
  } else {
    MM(0, 0)
  }
#undef LA
#undef LB
#undef LAX
#undef LBX
#undef MM

  // scatter partials: row = b-local, col = h-local (validated mapping)
#pragma unroll
  for (int pi = 0; pi < 2; ++pi)
#pragma unroll
    for (int qi = 0; qi < 4; ++qi) {
      const int row = pi * 16 + ((lane >> 4) << 2);
      const int col = qi * 16 + (lane & 15);
#pragma unroll
      for (int r = 0; r < 4; ++r)
        ldsC[w][row + r][col] =
            acc1[pi][qi][r] + acc2[pi][qi][r] * (1.0f / 2048.0f);
    }
  __syncthreads();

  if (tid >= 512) return;

  // ---- reduce 16 partials + state update + pack next A (threads 0..511) ----
  f32x4 sum = {0.0f, 0.0f, 0.0f, 0.0f};
#pragma unroll
  for (int ww = 0; ww < 16; ++ww)
    sum += *reinterpret_cast<const f32x4*>(&ldsC[ww][bl][q * 4]);

  const f32x4 sv = *reinterpret_cast<const f32x4*>(&state[e0]);
  const f32x4 bi = *reinterpret_cast<const f32x4*>(&b_in[h0]);
  const f32x4 br = *reinterpret_cast<const f32x4*>(&b_rec[h0]);
  f32x4 so, oo;
  f16x4 vh, vm;
#pragma unroll
  for (int j = 0; j < 4; ++j) {
    float s = sv[j] * 0.6666666865348816f +
              (sum[j] + bi[j] + br[j]) * 0.3333333432674408f;
    s += sig * nz[j];
    const float o = fmaxf(s, 0.0f);
    so[j] = s; oo[j] = o;
    _Float16 xh, xm;
    split2(o, xh, xm);
    vh[j] = xh; vm[j] = xm;
  }
  *reinterpret_cast<f32x4*>(&state[e0]) = so;
  *reinterpret_cast<f32x4*>(&out_t[e0]) = oo;

  const int b = b0 + bl;
  _Float16* dst = Apk_next +
      ((size_t)((b >> 4) * NSTEP_REC + hb * 2 + (q >> 3)) * 2) * 512 +
      ((b & 15) + 16 * ((q >> 1) & 3)) * 8 + (q & 1) * 4;
  *reinterpret_cast<f16x4*>(dst)       = vh;
  *reinterpret_cast<f16x4*>(dst + 512) = vm;
}

__global__ void finalize_kernel(const float* __restrict__ state,
                                const float* __restrict__ last_out,
                                float* __restrict__ dst) {
  const int i = blockIdx.x * 256 + threadIdx.x;
  dst[i] = state[i];
  dst[BH + i] = last_out[i];
}

extern "C" void kernel_launch(void* const* d_in, const int* in_sizes, int n_in,
                              void* d_out, int out_size, void* d_ws, size_t ws_size,
                              hipStream_t stream) {
  const float* inputs = (const float*)d_in[0];
  const float* W_in   = (const float*)d_in[1];
  const float* b_in   = (const float*)d_in[2];
  const float* W_rec  = (const float*)d_in[3];
  const float* b_rec  = (const float*)d_in[4];
  float* out = (float*)d_out;

  char* ws = (char*)d_ws;
  _Float16* Bpk = (_Float16*)ws;                 // 13,991,936 B
  _Float16* Xpk = (_Float16*)(ws + 13991936);    // 41,943,040 B
  _Float16* Apk = (_Float16*)(ws + 55934976);    // 3,670,016 B
  float* state  = (float*)(ws + 59604992);       // 1,835,008 B
  unsigned* keybuf = (unsigned*)(ws + 61440000); // 2,048 B

  init_keys_kernel<<<1, 256, 0, stream>>>(keybuf);
  pack_B_kernel<<<1708, 256, 0, stream>>>(W_in, W_rec, Bpk);
  pack_x_kernel<<<5120, 256, 0, stream>>>(inputs, Xpk);
  zero_kernel<<<1792, 256, 0, stream>>>(state, BH);
  zero_kernel<<<1792, 256, 0, stream>>>((float*)Apk, APK_HALF / 2);

  for (int t = 0; t < T_STEPS; ++t) {
    const int par = t & 1;
    eirnn_step<<<224, 1024, 0, stream>>>(
        Apk + (size_t)par * APK_HALF,
        Apk + (size_t)(par ^ 1) * APK_HALF,
        Xpk + (size_t)t * (16 * NSTEP_X * 2 * 512),
        Bpk, state, b_in, b_rec, keybuf, out + (size_t)t * BH, t);
  }

  finalize_kernel<<<1792, 256, 0, stream>>>(
      state, out + (size_t)(T_STEPS - 1) * BH, out + (size_t)T_STEPS * BH);
}